// Round 11
// baseline (332.834 us; speedup 1.0000x reference)
//
#include <hip/hip_runtime.h>
#include <hip/hip_bf16.h>

#define DEV static __device__ __forceinline__

typedef short bf16x8 __attribute__((ext_vector_type(8)));
typedef float f32x4  __attribute__((ext_vector_type(4)));
typedef unsigned u32x4 __attribute__((ext_vector_type(4)));
typedef unsigned u32x2 __attribute__((ext_vector_type(2)));

union U4 { uint4 u; bf16x8 s; };

DEV float b2f(__hip_bfloat16 v) { return __bfloat162float(v); }
DEV float lrelu(float e) { return e > 0.f ? e : 0.2f * e; }

DEV unsigned short f2bu(float f) {
    __hip_bfloat16 b = __float2bfloat16(f);
    return *reinterpret_cast<unsigned short*>(&b);
}
DEV float bu2f(unsigned short u) { return __uint_as_float((unsigned)u << 16); }

DEV float loadF(const void* p, size_t i, int f32) {
    if (f32) return ((const float*)p)[i];
    return b2f(((const __hip_bfloat16*)p)[i]);
}

DEV uint4 pack8(const unsigned short* t) {
    uint4 v;
    v.x = (unsigned)t[0] | ((unsigned)t[1] << 16);
    v.y = (unsigned)t[2] | ((unsigned)t[3] << 16);
    v.z = (unsigned)t[4] | ((unsigned)t[5] << 16);
    v.w = (unsigned)t[6] | ((unsigned)t[7] << 16);
    return v;
}

DEV u32x4 pack8v(const unsigned short* t) {
    u32x4 v;
    v.x = (unsigned)t[0] | ((unsigned)t[1] << 16);
    v.y = (unsigned)t[2] | ((unsigned)t[3] << 16);
    v.z = (unsigned)t[4] | ((unsigned)t[5] << 16);
    v.w = (unsigned)t[6] | ((unsigned)t[7] << 16);
    return v;
}

DEV void edge_sd(int i, int E, const int* __restrict__ src, const int* __restrict__ dst,
                 int& s, int& d) {
    if (i < E) { s = src[i]; d = dst[i]; }
    else       { s = d = i - E; }  // self-loops appended as arange(N)
}

// ---------------- binned CSR build + fused dtype detect ----------------
#define G_BIN 128

// blocks 0..G_BIN-1: coarse histogram; block G_BIN: dtype detection
// (one wave per 1-2 arrays, 256 samples each, ballot-reduced).
__global__ __launch_bounds__(256) void k_binA(
    const int* __restrict__ src, const int* __restrict__ dst,
    int* __restrict__ hist, int E, int EA, int chunk,
    const void* a0, int n0, const void* a1, int n1, const void* a2, int n2,
    const void* a3, int n3, const void* a4, int n4, const void* a5, int n5,
    const void* a6, int n6, const void* a7, int n7, const void* a8, int n8,
    int* __restrict__ flags)
{
    const int tid = threadIdx.x;
    if (blockIdx.x == G_BIN) {
        const void* ps[9] = {a0,a1,a2,a3,a4,a5,a6,a7,a8};
        const int   ns[9] = {n0,n1,n2,n3,n4,n5,n6,n7,n8};
        const int w = tid >> 6, lane = tid & 63;
        for (int k = w; k < 9; k += 4) {
            const unsigned short* p = (const unsigned short*)ps[k];
            const int n = ns[k];
            bool insane = false;
#pragma unroll
            for (int r = 0; r < 4; ++r) {
                int idx = lane + r * 64;
                if (idx < n) {
                    unsigned short u = p[idx];
                    unsigned e = (u >> 7) & 0xFFu;
                    insane |= (e >= 0xC8u) || (e == 0u && (u & 0x7Fu) != 0u);
                }
            }
            unsigned long long m = __ballot(insane);
            if (lane == 0) flags[k] = (m != 0ull) ? 1 : 0;
        }
        return;
    }
    __shared__ int cnt[256];
    cnt[tid] = 0;
    __syncthreads();
    const int lo = blockIdx.x * chunk;
    const int hi = min(lo + chunk, EA);
    for (int i = lo + tid; i < hi; i += 256) {
        int s, d; edge_sd(i, E, src, dst, s, d);
        atomicAdd(&cnt[d >> 8], 1);
    }
    __syncthreads();
    hist[blockIdx.x * 256 + tid] = cnt[tid];
}

__global__ __launch_bounds__(G_BIN) void k_binB1(
    const int* __restrict__ hist, int* __restrict__ offs_rel,
    int* __restrict__ btot)
{
    __shared__ int sm[G_BIN];
    const int t = threadIdx.x;
    const int b = blockIdx.x;
    int v = hist[t * 256 + b];
    sm[t] = v;
    __syncthreads();
#pragma unroll
    for (int off = 1; off < G_BIN; off <<= 1) {
        int u = (t >= off) ? sm[t - off] : 0;
        __syncthreads();
        sm[t] += u;
        __syncthreads();
    }
    offs_rel[t * 256 + b] = sm[t] - v;
    if (t == G_BIN - 1) btot[b] = sm[t];
}

__global__ __launch_bounds__(256) void k_binB2(
    const int* __restrict__ btot, int* __restrict__ bstart)
{
    __shared__ int sm[256];
    const int tid = threadIdx.x;
    int v = btot[tid];
    sm[tid] = v;
    __syncthreads();
#pragma unroll
    for (int off = 1; off < 256; off <<= 1) {
        int t = (tid >= off) ? sm[tid - off] : 0;
        __syncthreads();
        sm[tid] += t;
        __syncthreads();
    }
    bstart[tid] = sm[tid] - v;
    if (tid == 255) bstart[256] = sm[255];
}

__global__ __launch_bounds__(256) void k_binC(
    const int* __restrict__ src, const int* __restrict__ dst,
    const int* __restrict__ offs_rel, const int* __restrict__ bstart,
    unsigned* __restrict__ ebuf, int E, int EA, int chunk)
{
    __shared__ int cur[256];
    const int tid = threadIdx.x;
    cur[tid] = bstart[tid] + offs_rel[blockIdx.x * 256 + tid];
    __syncthreads();
    const int lo = blockIdx.x * chunk;
    const int hi = min(lo + chunk, EA);
    for (int i = lo + tid; i < hi; i += 256) {
        int s, d; edge_sd(i, E, src, dst, s, d);
        int pos = atomicAdd(&cur[d >> 8], 1);
        ebuf[pos] = ((unsigned)(d & 255) << 17) | (unsigned)s;
    }
}

__global__ __launch_bounds__(256) void k_binD(
    const unsigned* __restrict__ ebuf, const int* __restrict__ bstart,
    int* __restrict__ row_ptr, int* __restrict__ col, int N)
{
    __shared__ int cnt[256];
    __shared__ int pfx[256];
    const int tid = threadIdx.x;
    const int b = blockIdx.x;
    const int lo = bstart[b], hi = bstart[b + 1];
    cnt[tid] = 0;
    __syncthreads();
    for (int i = lo + tid; i < hi; i += 256)
        atomicAdd(&cnt[ebuf[i] >> 17], 1);
    __syncthreads();
    const int c = cnt[tid];
    pfx[tid] = c;
    __syncthreads();
#pragma unroll
    for (int off = 1; off < 256; off <<= 1) {
        int t = (tid >= off) ? pfx[tid - off] : 0;
        __syncthreads();
        pfx[tid] += t;
        __syncthreads();
    }
    const int excl = pfx[tid] - c;
    const int d = b * 256 + tid;
    if (d <= N) row_ptr[d] = lo + excl;
    __syncthreads();
    cnt[tid] = lo + excl;
    __syncthreads();
    for (int i = lo + tid; i < hi; i += 256) {
        unsigned v = ebuf[i];
        int pos = atomicAdd(&cnt[v >> 17], 1);
        col[pos] = (int)(v & 0x1FFFFu);
    }
}

// ---------------- MFMA layer-1 GEMM: h = x(N,128)@W1(128,64) + fused logits ----------------
__global__ __launch_bounds__(256) void k_gemm1(
    const void* __restrict__ x, const void* __restrict__ W,
    const void* __restrict__ a_s, const void* __restrict__ a_d,
    const int* __restrict__ flags,
    __hip_bfloat16* __restrict__ h, float* __restrict__ als, float* __restrict__ ald,
    int N)
{
    __shared__ __align__(16) unsigned short sMem[2 * 64 * 136];
    __shared__ float sAs[64], sAd[64];
    unsigned short* sA = sMem;
    unsigned short* sB = sMem + 64 * 136;
    float* sOut = (float*)sMem;

    const int tid = threadIdx.x;
    const int row0 = blockIdx.x * 64;
    const int fx = flags[0], fw = flags[1];

    if (tid < 64) sAs[tid] = loadF(a_s, tid, flags[2]);
    else if (tid < 128) sAd[tid - 64] = loadF(a_d, tid - 64, flags[3]);

    if (!fx) {
        const uint4* xg = (const uint4*)x;
#pragma unroll
        for (int it = 0; it < 2; ++it) {
            int g = tid + it * 256;
            int r = g >> 4, c16 = g & 15;
            uint4 v = (row0 + r < N) ? xg[(size_t)(row0 + r) * 16 + c16]
                                     : make_uint4(0, 0, 0, 0);
            *(uint4*)(sA + r * 136 + c16 * 8) = v;
        }
    } else {
        for (int i = tid; i < 64 * 128; i += 256) {
            int r = i >> 7, k = i & 127;
            float v = (row0 + r < N) ? ((const float*)x)[(size_t)(row0 + r) * 128 + k] : 0.f;
            sA[r * 136 + k] = f2bu(v);
        }
    }
    if (!fw) {
        const unsigned short* Wg = (const unsigned short*)W;
        const int n = tid & 63;
        int k0 = (tid >> 6) * 8;
#pragma unroll
        for (int rep = 0; rep < 4; ++rep, k0 += 32) {
            unsigned short t[8];
#pragma unroll
            for (int j = 0; j < 8; ++j) t[j] = Wg[(size_t)(k0 + j) * 64 + n];
            *(uint4*)(sB + n * 136 + k0) = pack8(t);
        }
    } else {
        const float* Wg = (const float*)W;
        for (int i = tid; i < 128 * 64; i += 256) {
            int k = i >> 6, n = i & 63;
            sB[n * 136 + k] = f2bu(Wg[i]);
        }
    }
    __syncthreads();

    const int w = tid >> 6, lane = tid & 63;
    const int m0 = w * 16;
    const int qr = lane >> 4;
    const int lc = lane & 15;

    bf16x8 afrag[4];
#pragma unroll
    for (int c = 0; c < 4; ++c) {
        U4 u; u.u = *(const uint4*)(sA + (m0 + lc) * 136 + c * 32 + qr * 8);
        afrag[c] = u.s;
    }
    f32x4 accs[4];
#pragma unroll
    for (int nt = 0; nt < 4; ++nt) {
        f32x4 acc = {0.f, 0.f, 0.f, 0.f};
#pragma unroll
        for (int c = 0; c < 4; ++c) {
            U4 u; u.u = *(const uint4*)(sB + (nt * 16 + lc) * 136 + c * 32 + qr * 8);
            acc = __builtin_amdgcn_mfma_f32_16x16x32_bf16(afrag[c], u.s, acc, 0, 0, 0);
        }
        accs[nt] = acc;
    }
    __syncthreads();

#pragma unroll
    for (int nt = 0; nt < 4; ++nt)
#pragma unroll
        for (int reg = 0; reg < 4; ++reg)
            sOut[(m0 + qr * 4 + reg) * 68 + nt * 16 + lc] = accs[nt][reg];
    __syncthreads();

    {
        const int r = tid >> 2, seg = tid & 3;
        const int row = row0 + r;
        const float* po = sOut + r * 68 + seg * 16;
        float ps = 0.f, pd = 0.f;
        unsigned short ob[16];
#pragma unroll
        for (int i = 0; i < 16; ++i) {
            float v = po[i];
            ps = fmaf(v, sAs[seg * 16 + i], ps);
            pd = fmaf(v, sAd[seg * 16 + i], pd);
            ob[i] = f2bu(v);
        }
        if (row < N) {
            uint4* hp = (uint4*)((unsigned short*)h + (size_t)row * 64 + seg * 16);
            hp[0] = pack8(ob);
            hp[1] = pack8(ob + 8);
        }
        ps += __shfl_xor(ps, 1, 64); ps += __shfl_xor(ps, 2, 64);
        pd += __shfl_xor(pd, 1, 64); pd += __shfl_xor(pd, 2, 64);
        if (seg == 0 && row < N) { als[row] = ps; ald[row] = pd; }
    }
}

// ---------------- gather-1 with FUSED layer-2 gemm (64x64 matvec in-wave) ----------------
// lane = sub*16 + eg*8 + fg. After the edge loop + xor-8 reduction, all 16
// lanes of a subgroup hold the node's 64-feature aggregate. Epilogue computes
// h2 = relu(agg+b1)@W2 via LDS-staged W2 + 8 broadcasts, plus als2/ald2 dots.
// Replaces k_gemm2 entirely (no agg round-trip).
__global__ __launch_bounds__(256) void k_gather1(
    const int* __restrict__ row_ptr, const int* __restrict__ col,
    const float* __restrict__ als, const float* __restrict__ ald,
    const __hip_bfloat16* __restrict__ h,
    const void* __restrict__ b1, const void* __restrict__ W2,
    const void* __restrict__ as2, const void* __restrict__ ad2,
    const int* __restrict__ flags,
    __hip_bfloat16* __restrict__ h2, float* __restrict__ als2,
    float* __restrict__ ald2, int N)
{
    __shared__ float sW2[64 * 64];       // [k][n]
    __shared__ float sB1[64], sAs2[64], sAd2[64];
    const int tid = threadIdx.x;
    {
        const int fw2 = flags[5];
        for (int i = tid; i < 64 * 64; i += 256) sW2[i] = loadF(W2, i, fw2);
        if (tid < 64) sB1[tid] = loadF(b1, tid, flags[4]);
        else if (tid < 128) sAs2[tid - 64] = loadF(as2, tid - 64, flags[6]);
        else if (tid < 192) sAd2[tid - 128] = loadF(ad2, tid - 128, flags[7]);
    }
    __syncthreads();

    const int lane = tid & 63;
    const int sub = lane >> 4;
    const int eg  = (lane >> 3) & 1;
    const int fg  = lane & 7;
    const int lane16 = lane & 15;
    const int wslot = blockIdx.x * 4 + (tid >> 6);
    const int stride = gridDim.x * 4 * 4;

    for (int d0 = wslot * 4; d0 < N; d0 += stride) {
        const int d = d0 + sub;
        const bool valid = d < N;
        int beg = 0, end = 0; float aldd = 0.f;
        if (valid) { beg = row_ptr[d]; end = row_ptr[d + 1]; aldd = ald[d]; }
        float acc[8] = {0.f,0.f,0.f,0.f,0.f,0.f,0.f,0.f};
        float den = 0.f;
        for (int j = beg + eg; valid && j < end; j += 2) {   // per-lane exit
            const int s = col[j];
            const float w = __expf(lrelu(als[s] + aldd));
            den += w;
            const uint4 hv = *(const uint4*)(h + (size_t)s * 64 + fg * 8);
            acc[0] = fmaf(w, __uint_as_float(hv.x << 16),          acc[0]);
            acc[1] = fmaf(w, __uint_as_float(hv.x & 0xFFFF0000u),  acc[1]);
            acc[2] = fmaf(w, __uint_as_float(hv.y << 16),          acc[2]);
            acc[3] = fmaf(w, __uint_as_float(hv.y & 0xFFFF0000u),  acc[3]);
            acc[4] = fmaf(w, __uint_as_float(hv.z << 16),          acc[4]);
            acc[5] = fmaf(w, __uint_as_float(hv.z & 0xFFFF0000u),  acc[5]);
            acc[6] = fmaf(w, __uint_as_float(hv.w << 16),          acc[6]);
            acc[7] = fmaf(w, __uint_as_float(hv.w & 0xFFFF0000u),  acc[7]);
        }
        den += __shfl_xor(den, 8, 64);
#pragma unroll
        for (int k = 0; k < 8; ++k) acc[k] += __shfl_xor(acc[k], 8, 64);

        // x_in = relu(agg + b1) for this lane's fg bank (fp32, no bf16 round-trip)
        const float inv = 1.f / den;
        float xk[8];
#pragma unroll
        for (int k = 0; k < 8; ++k) {
            float t = acc[k] * inv + sB1[fg * 8 + k];
            xk[k] = t > 0.f ? t : 0.f;
        }
        // matvec: lane computes outputs n in [ofs, ofs+4)
        float o[4] = {0.f, 0.f, 0.f, 0.f};
        const int ofs = lane16 * 4;
#pragma unroll
        for (int fs = 0; fs < 8; ++fs) {
            float xb[8];
#pragma unroll
            for (int k = 0; k < 8; ++k) xb[k] = __shfl(xk[k], (sub << 4) + fs, 64);
#pragma unroll
            for (int k = 0; k < 8; ++k) {
                const float* wr = &sW2[(fs * 8 + k) * 64 + ofs];
                o[0] = fmaf(xb[k], wr[0], o[0]);
                o[1] = fmaf(xb[k], wr[1], o[1]);
                o[2] = fmaf(xb[k], wr[2], o[2]);
                o[3] = fmaf(xb[k], wr[3], o[3]);
            }
        }
        // layer-2 logits
        float ps = o[0] * sAs2[ofs]     + o[1] * sAs2[ofs + 1]
                 + o[2] * sAs2[ofs + 2] + o[3] * sAs2[ofs + 3];
        float pd = o[0] * sAd2[ofs]     + o[1] * sAd2[ofs + 1]
                 + o[2] * sAd2[ofs + 2] + o[3] * sAd2[ofs + 3];
#pragma unroll
        for (int off = 1; off <= 8; off <<= 1) {
            ps += __shfl_xor(ps, off, 64);
            pd += __shfl_xor(pd, off, 64);
        }
        if (valid) {
            if (lane16 == 0) { als2[d] = ps; ald2[d] = pd; }
            unsigned short ob[4] = {f2bu(o[0]), f2bu(o[1]), f2bu(o[2]), f2bu(o[3])};
            u32x2 st;
            st.x = (unsigned)ob[0] | ((unsigned)ob[1] << 16);
            st.y = (unsigned)ob[2] | ((unsigned)ob[3] << 16);
            *(u32x2*)((unsigned short*)h2 + (size_t)d * 64 + ofs) = st;
        }
    }
}

// ---------------- gather-2: final aggregation + bias + output store ----------------
__global__ __launch_bounds__(256) void k_gather2(
    const int* __restrict__ row_ptr, const int* __restrict__ col,
    const float* __restrict__ als, const float* __restrict__ ald,
    const __hip_bfloat16* __restrict__ h,
    void* __restrict__ out, const void* __restrict__ bias,
    const int* __restrict__ flags, int N)
{
    const int tid = threadIdx.x;
    const int lane = tid & 63;
    const int sub = lane >> 4;
    const int eg  = (lane >> 3) & 1;
    const int fg  = lane & 7;
    const int wslot = blockIdx.x * 4 + (tid >> 6);
    const int stride = gridDim.x * 4 * 4;

    for (int d0 = wslot * 4; d0 < N; d0 += stride) {
        const int d = d0 + sub;
        const bool valid = d < N;
        int beg = 0, end = 0; float aldd = 0.f;
        if (valid) { beg = row_ptr[d]; end = row_ptr[d + 1]; aldd = ald[d]; }
        float acc[8] = {0.f,0.f,0.f,0.f,0.f,0.f,0.f,0.f};
        float den = 0.f;
        for (int j = beg + eg; valid && j < end; j += 2) {   // per-lane exit
            const int s = col[j];
            const float w = __expf(lrelu(als[s] + aldd));
            den += w;
            const uint4 hv = *(const uint4*)(h + (size_t)s * 64 + fg * 8);
            acc[0] = fmaf(w, __uint_as_float(hv.x << 16),          acc[0]);
            acc[1] = fmaf(w, __uint_as_float(hv.x & 0xFFFF0000u),  acc[1]);
            acc[2] = fmaf(w, __uint_as_float(hv.y << 16),          acc[2]);
            acc[3] = fmaf(w, __uint_as_float(hv.y & 0xFFFF0000u),  acc[3]);
            acc[4] = fmaf(w, __uint_as_float(hv.z << 16),          acc[4]);
            acc[5] = fmaf(w, __uint_as_float(hv.z & 0xFFFF0000u),  acc[5]);
            acc[6] = fmaf(w, __uint_as_float(hv.w << 16),          acc[6]);
            acc[7] = fmaf(w, __uint_as_float(hv.w & 0xFFFF0000u),  acc[7]);
        }
        den += __shfl_xor(den, 8, 64);
#pragma unroll
        for (int k = 0; k < 8; ++k) acc[k] += __shfl_xor(acc[k], 8, 64);

        if (eg == 0 && valid) {
            const float inv = 1.f / den;
            float vb[8];
#pragma unroll
            for (int k = 0; k < 8; ++k) vb[k] = acc[k] * inv + loadF(bias, fg * 8 + k, flags[8]);
            if (flags[0]) {
                float* o = (float*)out + (size_t)d * 64 + fg * 8;
                f32x4 o0 = {vb[0], vb[1], vb[2], vb[3]};
                f32x4 o1 = {vb[4], vb[5], vb[6], vb[7]};
                __builtin_nontemporal_store(o0, (f32x4*)o);
                __builtin_nontemporal_store(o1, (f32x4*)(o + 4));
            } else {
                unsigned short ob[8];
#pragma unroll
                for (int k = 0; k < 8; ++k) ob[k] = f2bu(vb[k]);
                __builtin_nontemporal_store(pack8v(ob),
                    reinterpret_cast<u32x4*>((__hip_bfloat16*)out + (size_t)d * 64 + fg * 8));
            }
        }
    }
}

extern "C" void kernel_launch(void* const* d_in, const int* in_sizes, int n_in,
                              void* d_out, int out_size, void* d_ws, size_t ws_size,
                              hipStream_t stream)
{
    const void* x   = d_in[0];
    const int*  ei  = (const int*)d_in[1];
    const void* W1  = d_in[2];
    const void* as1 = d_in[3];
    const void* ad1 = d_in[4];
    const void* b1  = d_in[5];
    const void* W2  = d_in[6];
    const void* as2 = d_in[7];
    const void* ad2 = d_in[8];
    const void* b2  = d_in[9];

    const int N  = in_sizes[0] / 128;   // 50000
    const int E  = in_sizes[1] / 2;     // 800000
    const int EA = E + N;
    const int* src = ei;
    const int* dst = ei + E;

    uintptr_t base = (uintptr_t)d_ws;
    auto alloc = [&](size_t bytes) { uintptr_t p = base; base += (bytes + 63) & ~(size_t)63; return p; };
    int*      flags    = (int*)alloc(64 * 4);
    float*    als      = (float*)alloc((size_t)N * 4);
    float*    ald      = (float*)alloc((size_t)N * 4);
    float*    als2     = (float*)alloc((size_t)N * 4);
    float*    ald2     = (float*)alloc((size_t)N * 4);
    int*      row_ptr  = (int*)alloc((size_t)(N + 1) * 4);
    int*      hist     = (int*)alloc((size_t)G_BIN * 256 * 4);
    int*      offs_rel = (int*)alloc((size_t)G_BIN * 256 * 4);
    int*      btot     = (int*)alloc(256 * 4);
    int*      bstart   = (int*)alloc(257 * 4);
    unsigned* ebuf     = (unsigned*)alloc((size_t)EA * 4);
    int*      col      = (int*)alloc((size_t)EA * 4);
    __hip_bfloat16* hbuf  = (__hip_bfloat16*)alloc((size_t)N * 64 * 2);
    __hip_bfloat16* h2buf = (__hip_bfloat16*)alloc((size_t)N * 64 * 2);

    const int gatherb = 2048;             // persistent: 8 blocks/CU resident
    const int gb  = (N + 63) / 64;        // mfma gemm: 64 rows/block
    const int NBK = (N + 255) / 256;      // dst buckets (<= 256)
    const int chunk = (EA + G_BIN - 1) / G_BIN;

    // ---- CSR build + dtype detect (binA block G_BIN) ----
    k_binA<<<G_BIN + 1, 256, 0, stream>>>(
        src, dst, hist, E, EA, chunk,
        x, in_sizes[0], W1, in_sizes[2], as1, in_sizes[3], ad1, in_sizes[4],
        b1, in_sizes[5], W2, in_sizes[6], as2, in_sizes[7], ad2, in_sizes[8],
        b2, in_sizes[9], flags);
    k_binB1<<<256, G_BIN, 0, stream>>>(hist, offs_rel, btot);
    k_binB2<<<1, 256, 0, stream>>>(btot, bstart);
    k_binC<<<G_BIN, 256, 0, stream>>>(src, dst, offs_rel, bstart, ebuf, E, EA, chunk);
    k_binD<<<NBK, 256, 0, stream>>>(ebuf, bstart, row_ptr, col, N);

    // ---- layer 1 GEMM + fused gather-1 (incl. layer-2 gemm + logits) ----
    k_gemm1<<<gb, 256, 0, stream>>>(x, W1, as1, ad1, flags, hbuf, als, ald, N);
    k_gather1<<<gatherb, 256, 0, stream>>>(row_ptr, col, als, ald, hbuf,
                                           b1, W2, as2, ad2, flags,
                                           h2buf, als2, ald2, N);
    // ---- layer 2 gather -> output ----
    k_gather2<<<gatherb, 256, 0, stream>>>(row_ptr, col, als2, ald2, h2buf,
                                           d_out, b2, flags, N);
    (void)out_size; (void)ws_size; (void)n_in;
}

// Round 12
// 210.972 us; speedup vs baseline: 1.5776x; 1.5776x over previous
//
#include <hip/hip_runtime.h>
#include <hip/hip_bf16.h>

#define DEV static __device__ __forceinline__

typedef short bf16x8 __attribute__((ext_vector_type(8)));
typedef float f32x4  __attribute__((ext_vector_type(4)));
typedef unsigned u32x4 __attribute__((ext_vector_type(4)));

union U4 { uint4 u; bf16x8 s; };

DEV float b2f(__hip_bfloat16 v) { return __bfloat162float(v); }
DEV float lrelu(float e) { return e > 0.f ? e : 0.2f * e; }

DEV unsigned short f2bu(float f) {
    __hip_bfloat16 b = __float2bfloat16(f);
    return *reinterpret_cast<unsigned short*>(&b);
}
DEV float bu2f(unsigned short u) { return __uint_as_float((unsigned)u << 16); }

DEV float loadF(const void* p, size_t i, int f32) {
    if (f32) return ((const float*)p)[i];
    return b2f(((const __hip_bfloat16*)p)[i]);
}

DEV uint4 pack8(const unsigned short* t) {
    uint4 v;
    v.x = (unsigned)t[0] | ((unsigned)t[1] << 16);
    v.y = (unsigned)t[2] | ((unsigned)t[3] << 16);
    v.z = (unsigned)t[4] | ((unsigned)t[5] << 16);
    v.w = (unsigned)t[6] | ((unsigned)t[7] << 16);
    return v;
}

DEV u32x4 pack8v(const unsigned short* t) {
    u32x4 v;
    v.x = (unsigned)t[0] | ((unsigned)t[1] << 16);
    v.y = (unsigned)t[2] | ((unsigned)t[3] << 16);
    v.z = (unsigned)t[4] | ((unsigned)t[5] << 16);
    v.w = (unsigned)t[6] | ((unsigned)t[7] << 16);
    return v;
}

DEV void edge_sd(int i, int E, const int* __restrict__ src, const int* __restrict__ dst,
                 int& s, int& d) {
    if (i < E) { s = src[i]; d = dst[i]; }
    else       { s = d = i - E; }  // self-loops appended as arange(N)
}

// ---------------- binned CSR build + fused dtype detect ----------------
#define G_BIN 128

// blocks 0..G_BIN-1: coarse histogram; block G_BIN: dtype detection.
__global__ __launch_bounds__(256) void k_binA(
    const int* __restrict__ src, const int* __restrict__ dst,
    int* __restrict__ hist, int E, int EA, int chunk,
    const void* a0, int n0, const void* a1, int n1, const void* a2, int n2,
    const void* a3, int n3, const void* a4, int n4, const void* a5, int n5,
    const void* a6, int n6, const void* a7, int n7, const void* a8, int n8,
    int* __restrict__ flags)
{
    const int tid = threadIdx.x;
    if (blockIdx.x == G_BIN) {
        const void* ps[9] = {a0,a1,a2,a3,a4,a5,a6,a7,a8};
        const int   ns[9] = {n0,n1,n2,n3,n4,n5,n6,n7,n8};
        const int w = tid >> 6, lane = tid & 63;
        for (int k = w; k < 9; k += 4) {
            const unsigned short* p = (const unsigned short*)ps[k];
            const int n = ns[k];
            bool insane = false;
#pragma unroll
            for (int r = 0; r < 4; ++r) {
                int idx = lane + r * 64;
                if (idx < n) {
                    unsigned short u = p[idx];
                    unsigned e = (u >> 7) & 0xFFu;
                    insane |= (e >= 0xC8u) || (e == 0u && (u & 0x7Fu) != 0u);
                }
            }
            unsigned long long m = __ballot(insane);
            if (lane == 0) flags[k] = (m != 0ull) ? 1 : 0;
        }
        return;
    }
    __shared__ int cnt[256];
    cnt[tid] = 0;
    __syncthreads();
    const int lo = blockIdx.x * chunk;
    const int hi = min(lo + chunk, EA);
    for (int i = lo + tid; i < hi; i += 256) {
        int s, d; edge_sd(i, E, src, dst, s, d);
        atomicAdd(&cnt[d >> 8], 1);
    }
    __syncthreads();
    hist[blockIdx.x * 256 + tid] = cnt[tid];
}

__global__ __launch_bounds__(G_BIN) void k_binB1(
    const int* __restrict__ hist, int* __restrict__ offs_rel,
    int* __restrict__ btot)
{
    __shared__ int sm[G_BIN];
    const int t = threadIdx.x;
    const int b = blockIdx.x;
    int v = hist[t * 256 + b];
    sm[t] = v;
    __syncthreads();
#pragma unroll
    for (int off = 1; off < G_BIN; off <<= 1) {
        int u = (t >= off) ? sm[t - off] : 0;
        __syncthreads();
        sm[t] += u;
        __syncthreads();
    }
    offs_rel[t * 256 + b] = sm[t] - v;
    if (t == G_BIN - 1) btot[b] = sm[t];
}

__global__ __launch_bounds__(256) void k_binB2(
    const int* __restrict__ btot, int* __restrict__ bstart)
{
    __shared__ int sm[256];
    const int tid = threadIdx.x;
    int v = btot[tid];
    sm[tid] = v;
    __syncthreads();
#pragma unroll
    for (int off = 1; off < 256; off <<= 1) {
        int t = (tid >= off) ? sm[tid - off] : 0;
        __syncthreads();
        sm[tid] += t;
        __syncthreads();
    }
    bstart[tid] = sm[tid] - v;
    if (tid == 255) bstart[256] = sm[255];
}

__global__ __launch_bounds__(256) void k_binC(
    const int* __restrict__ src, const int* __restrict__ dst,
    const int* __restrict__ offs_rel, const int* __restrict__ bstart,
    unsigned* __restrict__ ebuf, int E, int EA, int chunk)
{
    __shared__ int cur[256];
    const int tid = threadIdx.x;
    cur[tid] = bstart[tid] + offs_rel[blockIdx.x * 256 + tid];
    __syncthreads();
    const int lo = blockIdx.x * chunk;
    const int hi = min(lo + chunk, EA);
    for (int i = lo + tid; i < hi; i += 256) {
        int s, d; edge_sd(i, E, src, dst, s, d);
        int pos = atomicAdd(&cur[d >> 8], 1);
        ebuf[pos] = ((unsigned)(d & 255) << 17) | (unsigned)s;
    }
}

__global__ __launch_bounds__(256) void k_binD(
    const unsigned* __restrict__ ebuf, const int* __restrict__ bstart,
    int* __restrict__ row_ptr, int* __restrict__ col, int N)
{
    __shared__ int cnt[256];
    __shared__ int pfx[256];
    const int tid = threadIdx.x;
    const int b = blockIdx.x;
    const int lo = bstart[b], hi = bstart[b + 1];
    cnt[tid] = 0;
    __syncthreads();
    for (int i = lo + tid; i < hi; i += 256)
        atomicAdd(&cnt[ebuf[i] >> 17], 1);
    __syncthreads();
    const int c = cnt[tid];
    pfx[tid] = c;
    __syncthreads();
#pragma unroll
    for (int off = 1; off < 256; off <<= 1) {
        int t = (tid >= off) ? pfx[tid - off] : 0;
        __syncthreads();
        pfx[tid] += t;
        __syncthreads();
    }
    const int excl = pfx[tid] - c;
    const int d = b * 256 + tid;
    if (d <= N) row_ptr[d] = lo + excl;
    __syncthreads();
    cnt[tid] = lo + excl;
    __syncthreads();
    for (int i = lo + tid; i < hi; i += 256) {
        unsigned v = ebuf[i];
        int pos = atomicAdd(&cnt[v >> 17], 1);
        col[pos] = (int)(v & 0x1FFFFu);
    }
}

// ---------------- MFMA layer-1 GEMM: h = x(N,128)@W1(128,64) + fused logits ----------------
__global__ __launch_bounds__(256) void k_gemm1(
    const void* __restrict__ x, const void* __restrict__ W,
    const void* __restrict__ a_s, const void* __restrict__ a_d,
    const int* __restrict__ flags,
    __hip_bfloat16* __restrict__ h, float* __restrict__ als, float* __restrict__ ald,
    int N)
{
    __shared__ __align__(16) unsigned short sMem[2 * 64 * 136];
    __shared__ float sAs[64], sAd[64];
    unsigned short* sA = sMem;
    unsigned short* sB = sMem + 64 * 136;
    float* sOut = (float*)sMem;

    const int tid = threadIdx.x;
    const int row0 = blockIdx.x * 64;
    const int fx = flags[0], fw = flags[1];

    if (tid < 64) sAs[tid] = loadF(a_s, tid, flags[2]);
    else if (tid < 128) sAd[tid - 64] = loadF(a_d, tid - 64, flags[3]);

    if (!fx) {
        const uint4* xg = (const uint4*)x;
#pragma unroll
        for (int it = 0; it < 2; ++it) {
            int g = tid + it * 256;
            int r = g >> 4, c16 = g & 15;
            uint4 v = (row0 + r < N) ? xg[(size_t)(row0 + r) * 16 + c16]
                                     : make_uint4(0, 0, 0, 0);
            *(uint4*)(sA + r * 136 + c16 * 8) = v;
        }
    } else {
        for (int i = tid; i < 64 * 128; i += 256) {
            int r = i >> 7, k = i & 127;
            float v = (row0 + r < N) ? ((const float*)x)[(size_t)(row0 + r) * 128 + k] : 0.f;
            sA[r * 136 + k] = f2bu(v);
        }
    }
    if (!fw) {
        const unsigned short* Wg = (const unsigned short*)W;
        const int n = tid & 63;
        int k0 = (tid >> 6) * 8;
#pragma unroll
        for (int rep = 0; rep < 4; ++rep, k0 += 32) {
            unsigned short t[8];
#pragma unroll
            for (int j = 0; j < 8; ++j) t[j] = Wg[(size_t)(k0 + j) * 64 + n];
            *(uint4*)(sB + n * 136 + k0) = pack8(t);
        }
    } else {
        const float* Wg = (const float*)W;
        for (int i = tid; i < 128 * 64; i += 256) {
            int k = i >> 6, n = i & 63;
            sB[n * 136 + k] = f2bu(Wg[i]);
        }
    }
    __syncthreads();

    const int w = tid >> 6, lane = tid & 63;
    const int m0 = w * 16;
    const int qr = lane >> 4;
    const int lc = lane & 15;

    bf16x8 afrag[4];
#pragma unroll
    for (int c = 0; c < 4; ++c) {
        U4 u; u.u = *(const uint4*)(sA + (m0 + lc) * 136 + c * 32 + qr * 8);
        afrag[c] = u.s;
    }
    f32x4 accs[4];
#pragma unroll
    for (int nt = 0; nt < 4; ++nt) {
        f32x4 acc = {0.f, 0.f, 0.f, 0.f};
#pragma unroll
        for (int c = 0; c < 4; ++c) {
            U4 u; u.u = *(const uint4*)(sB + (nt * 16 + lc) * 136 + c * 32 + qr * 8);
            acc = __builtin_amdgcn_mfma_f32_16x16x32_bf16(afrag[c], u.s, acc, 0, 0, 0);
        }
        accs[nt] = acc;
    }
    __syncthreads();

#pragma unroll
    for (int nt = 0; nt < 4; ++nt)
#pragma unroll
        for (int reg = 0; reg < 4; ++reg)
            sOut[(m0 + qr * 4 + reg) * 68 + nt * 16 + lc] = accs[nt][reg];
    __syncthreads();

    {
        const int r = tid >> 2, seg = tid & 3;
        const int row = row0 + r;
        const float* po = sOut + r * 68 + seg * 16;
        float ps = 0.f, pd = 0.f;
        unsigned short ob[16];
#pragma unroll
        for (int i = 0; i < 16; ++i) {
            float v = po[i];
            ps = fmaf(v, sAs[seg * 16 + i], ps);
            pd = fmaf(v, sAd[seg * 16 + i], pd);
            ob[i] = f2bu(v);
        }
        if (row < N) {
            uint4* hp = (uint4*)((unsigned short*)h + (size_t)row * 64 + seg * 16);
            hp[0] = pack8(ob);
            hp[1] = pack8(ob + 8);
        }
        ps += __shfl_xor(ps, 1, 64); ps += __shfl_xor(ps, 2, 64);
        pd += __shfl_xor(pd, 1, 64); pd += __shfl_xor(pd, 2, 64);
        if (seg == 0 && row < N) { als[row] = ps; ald[row] = pd; }
    }
}

// ---------------- MFMA layer-2 GEMM: h2 = relu(agg+b1)@W2(64,64), in-place ----------------
__global__ __launch_bounds__(256) void k_gemm2(
    __hip_bfloat16* __restrict__ agg, const void* __restrict__ b1,
    const void* __restrict__ W, const void* __restrict__ a_s,
    const void* __restrict__ a_d, const int* __restrict__ flags,
    float* __restrict__ als, float* __restrict__ ald, int N)
{
    __shared__ __align__(16) unsigned short sMem[2 * 64 * 72];
    __shared__ float sAs[64], sAd[64], sBias[64];
    unsigned short* sA = sMem;
    unsigned short* sB = sMem + 64 * 72;
    float* sOut = (float*)sMem;

    const int tid = threadIdx.x;
    const int row0 = blockIdx.x * 64;
    const int fw = flags[5];

    if (tid < 64) sAs[tid] = loadF(a_s, tid, flags[6]);
    else if (tid < 128) sAd[tid - 64] = loadF(a_d, tid - 64, flags[7]);
    else if (tid < 192) sBias[tid - 128] = loadF(b1, tid - 128, flags[4]);
    __syncthreads();

    {
        const uint4* ag = (const uint4*)agg;
#pragma unroll
        for (int it = 0; it < 2; ++it) {
            int g = tid + it * 256;
            int r = g >> 3, c8 = g & 7;
            uint4 v = (row0 + r < N) ? ag[(size_t)(row0 + r) * 8 + c8]
                                     : make_uint4(0, 0, 0, 0);
            unsigned short in[8] = {
                (unsigned short)(v.x & 0xFFFF), (unsigned short)(v.x >> 16),
                (unsigned short)(v.y & 0xFFFF), (unsigned short)(v.y >> 16),
                (unsigned short)(v.z & 0xFFFF), (unsigned short)(v.z >> 16),
                (unsigned short)(v.w & 0xFFFF), (unsigned short)(v.w >> 16)};
            unsigned short ob[8];
#pragma unroll
            for (int j = 0; j < 8; ++j) {
                float t = bu2f(in[j]) + sBias[c8 * 8 + j];
                ob[j] = f2bu(t > 0.f ? t : 0.f);
            }
            *(uint4*)(sA + r * 72 + c8 * 8) = pack8(ob);
        }
    }
    if (!fw) {
        const unsigned short* Wg = (const unsigned short*)W;
        const int n = tid & 63;
        int k0 = (tid >> 6) * 8;
#pragma unroll
        for (int rep = 0; rep < 2; ++rep, k0 += 32) {
            unsigned short t[8];
#pragma unroll
            for (int j = 0; j < 8; ++j) t[j] = Wg[(size_t)(k0 + j) * 64 + n];
            *(uint4*)(sB + n * 72 + k0) = pack8(t);
        }
    } else {
        const float* Wg = (const float*)W;
        for (int i = tid; i < 64 * 64; i += 256) {
            int k = i >> 6, n = i & 63;
            sB[n * 72 + k] = f2bu(Wg[i]);
        }
    }
    __syncthreads();

    const int w = tid >> 6, lane = tid & 63;
    const int m0 = w * 16;
    const int qr = lane >> 4, lc = lane & 15;

    bf16x8 afrag[2];
#pragma unroll
    for (int c = 0; c < 2; ++c) {
        U4 u; u.u = *(const uint4*)(sA + (m0 + lc) * 72 + c * 32 + qr * 8);
        afrag[c] = u.s;
    }
    f32x4 accs[4];
#pragma unroll
    for (int nt = 0; nt < 4; ++nt) {
        f32x4 acc = {0.f, 0.f, 0.f, 0.f};
#pragma unroll
        for (int c = 0; c < 2; ++c) {
            U4 u; u.u = *(const uint4*)(sB + (nt * 16 + lc) * 72 + c * 32 + qr * 8);
            acc = __builtin_amdgcn_mfma_f32_16x16x32_bf16(afrag[c], u.s, acc, 0, 0, 0);
        }
        accs[nt] = acc;
    }
    __syncthreads();
#pragma unroll
    for (int nt = 0; nt < 4; ++nt)
#pragma unroll
        for (int reg = 0; reg < 4; ++reg)
            sOut[(m0 + qr * 4 + reg) * 68 + nt * 16 + lc] = accs[nt][reg];
    __syncthreads();

    {
        const int r = tid >> 2, seg = tid & 3;
        const int row = row0 + r;
        const float* po = sOut + r * 68 + seg * 16;
        float ps = 0.f, pd = 0.f;
        unsigned short ob[16];
#pragma unroll
        for (int i = 0; i < 16; ++i) {
            float v = po[i];
            ps = fmaf(v, sAs[seg * 16 + i], ps);
            pd = fmaf(v, sAd[seg * 16 + i], pd);
            ob[i] = f2bu(v);
        }
        if (row < N) {
            uint4* hp = (uint4*)((unsigned short*)agg + (size_t)row * 64 + seg * 16);
            hp[0] = pack8(ob);
            hp[1] = pack8(ob + 8);
        }
        ps += __shfl_xor(ps, 1, 64); ps += __shfl_xor(ps, 2, 64);
        pd += __shfl_xor(pd, 1, 64); pd += __shfl_xor(pd, 2, 64);
        if (seg == 0 && row < N) { als[row] = ps; ald[row] = pd; }
    }
}

// ---------------- CSR gather (r7 structure + per-cluster loop exit) ----------------
// Persistent waves, 1 node/wave, 8 edge slots x 8 feat groups x 16B.
// VGPR stays ~36 -> ~43% occupancy (r11 showed occupancy is the binding
// resource: 160 VGPR fused variant ran 3.7x slower).
__global__ __launch_bounds__(256) void k_gather(
    const int* __restrict__ row_ptr, const int* __restrict__ col,
    const float* __restrict__ als, const float* __restrict__ ald,
    const __hip_bfloat16* __restrict__ h,
    __hip_bfloat16* __restrict__ agg_out,
    void* __restrict__ final_out,
    const void* __restrict__ bias, const int* __restrict__ flags, int N)
{
    const int tid = threadIdx.x;
    const int lane = tid & 63;
    const int eg = lane >> 3, fg = lane & 7;
    const int wid = blockIdx.x * 4 + (tid >> 6);
    const int nw  = gridDim.x * 4;

    for (int d = wid; d < N; d += nw) {
        const float aldd = ald[d];
        const int beg = row_ptr[d], end = row_ptr[d + 1];
        float acc[8] = {0.f,0.f,0.f,0.f,0.f,0.f,0.f,0.f};
        float den = 0.f;
        for (int j = beg + eg; j < end; j += 8) {   // per-cluster exit: no dummy loads
            const int s = col[j];
            const float w = __expf(lrelu(als[s] + aldd));
            den += w;
            const uint4 hv = *reinterpret_cast<const uint4*>(h + (size_t)s * 64 + fg * 8);
            acc[0] = fmaf(w, __uint_as_float(hv.x << 16),          acc[0]);
            acc[1] = fmaf(w, __uint_as_float(hv.x & 0xFFFF0000u),  acc[1]);
            acc[2] = fmaf(w, __uint_as_float(hv.y << 16),          acc[2]);
            acc[3] = fmaf(w, __uint_as_float(hv.y & 0xFFFF0000u),  acc[3]);
            acc[4] = fmaf(w, __uint_as_float(hv.z << 16),          acc[4]);
            acc[5] = fmaf(w, __uint_as_float(hv.z & 0xFFFF0000u),  acc[5]);
            acc[6] = fmaf(w, __uint_as_float(hv.w << 16),          acc[6]);
            acc[7] = fmaf(w, __uint_as_float(hv.w & 0xFFFF0000u),  acc[7]);
        }
#pragma unroll
        for (int off = 8; off <= 32; off <<= 1) {
            den += __shfl_xor(den, off, 64);
#pragma unroll
            for (int k = 0; k < 8; ++k) acc[k] += __shfl_xor(acc[k], off, 64);
        }
        if (eg == 0) {
            const float inv = 1.f / den;
            if (final_out) {
                float vb[8];
#pragma unroll
                for (int k = 0; k < 8; ++k) vb[k] = acc[k] * inv + loadF(bias, fg * 8 + k, flags[8]);
                if (flags[0]) {
                    float* o = (float*)final_out + (size_t)d * 64 + fg * 8;
                    f32x4 o0 = {vb[0], vb[1], vb[2], vb[3]};
                    f32x4 o1 = {vb[4], vb[5], vb[6], vb[7]};
                    __builtin_nontemporal_store(o0, (f32x4*)o);
                    __builtin_nontemporal_store(o1, (f32x4*)(o + 4));
                } else {
                    unsigned short ob[8];
#pragma unroll
                    for (int k = 0; k < 8; ++k) ob[k] = f2bu(vb[k]);
                    __builtin_nontemporal_store(pack8v(ob),
                        reinterpret_cast<u32x4*>((__hip_bfloat16*)final_out + (size_t)d * 64 + fg * 8));
                }
            } else {
                unsigned short ob[8];
#pragma unroll
                for (int k = 0; k < 8; ++k) ob[k] = f2bu(acc[k] * inv);
                __builtin_nontemporal_store(pack8v(ob),
                    reinterpret_cast<u32x4*>(agg_out + (size_t)d * 64 + fg * 8));
            }
        }
    }
}

extern "C" void kernel_launch(void* const* d_in, const int* in_sizes, int n_in,
                              void* d_out, int out_size, void* d_ws, size_t ws_size,
                              hipStream_t stream)
{
    const void* x   = d_in[0];
    const int*  ei  = (const int*)d_in[1];
    const void* W1  = d_in[2];
    const void* as1 = d_in[3];
    const void* ad1 = d_in[4];
    const void* b1  = d_in[5];
    const void* W2  = d_in[6];
    const void* as2 = d_in[7];
    const void* ad2 = d_in[8];
    const void* b2  = d_in[9];

    const int N  = in_sizes[0] / 128;   // 50000
    const int E  = in_sizes[1] / 2;     // 800000
    const int EA = E + N;
    const int* src = ei;
    const int* dst = ei + E;

    uintptr_t base = (uintptr_t)d_ws;
    auto alloc = [&](size_t bytes) { uintptr_t p = base; base += (bytes + 63) & ~(size_t)63; return p; };
    int*      flags    = (int*)alloc(64 * 4);
    float*    als      = (float*)alloc((size_t)N * 4);
    float*    ald      = (float*)alloc((size_t)N * 4);
    int*      row_ptr  = (int*)alloc((size_t)(N + 1) * 4);
    int*      hist     = (int*)alloc((size_t)G_BIN * 256 * 4);
    int*      offs_rel = (int*)alloc((size_t)G_BIN * 256 * 4);
    int*      btot     = (int*)alloc(256 * 4);
    int*      bstart   = (int*)alloc(257 * 4);
    unsigned* ebuf     = (unsigned*)alloc((size_t)EA * 4);
    int*      col      = (int*)alloc((size_t)EA * 4);
    __hip_bfloat16* hbuf   = (__hip_bfloat16*)alloc((size_t)N * 64 * 2);
    __hip_bfloat16* aggbuf = (__hip_bfloat16*)alloc((size_t)N * 64 * 2);

    const int gatherb = 2048;             // persistent: 8 blocks/CU resident
    const int gb  = (N + 63) / 64;        // mfma gemm: 64 rows/block
    const int NBK = (N + 255) / 256;      // dst buckets (<= 256)
    const int chunk = (EA + G_BIN - 1) / G_BIN;

    // ---- CSR build + dtype detect (binA block G_BIN) ----
    k_binA<<<G_BIN + 1, 256, 0, stream>>>(
        src, dst, hist, E, EA, chunk,
        x, in_sizes[0], W1, in_sizes[2], as1, in_sizes[3], ad1, in_sizes[4],
        b1, in_sizes[5], W2, in_sizes[6], as2, in_sizes[7], ad2, in_sizes[8],
        b2, in_sizes[9], flags);
    k_binB1<<<256, G_BIN, 0, stream>>>(hist, offs_rel, btot);
    k_binB2<<<1, 256, 0, stream>>>(btot, bstart);
    k_binC<<<G_BIN, 256, 0, stream>>>(src, dst, offs_rel, bstart, ebuf, E, EA, chunk);
    k_binD<<<NBK, 256, 0, stream>>>(ebuf, bstart, row_ptr, col, N);

    // ---- layer 1 ----
    k_gemm1<<<gb, 256, 0, stream>>>(x, W1, as1, ad1, flags, hbuf, als, ald, N);
    k_gather<<<gatherb, 256, 0, stream>>>(row_ptr, col, als, ald, hbuf, aggbuf,
                                          nullptr, nullptr, flags, N);
    // ---- layer 2 ----
    k_gemm2<<<gb, 256, 0, stream>>>(aggbuf, b1, W2, as2, ad2, flags, als, ald, N);
    k_gather<<<gatherb, 256, 0, stream>>>(row_ptr, col, als, ald, aggbuf, nullptr,
                                          d_out, b2, flags, N);
    (void)out_size; (void)ws_size; (void)n_in;
}

// Round 13
// 200.612 us; speedup vs baseline: 1.6591x; 1.0516x over previous
//
#include <hip/hip_runtime.h>
#include <hip/hip_bf16.h>

#define DEV static __device__ __forceinline__

typedef short bf16x8 __attribute__((ext_vector_type(8)));
typedef float f32x4  __attribute__((ext_vector_type(4)));
typedef unsigned u32x4 __attribute__((ext_vector_type(4)));

union U4 { uint4 u; bf16x8 s; };

DEV float b2f(__hip_bfloat16 v) { return __bfloat162float(v); }
DEV float lrelu(float e) { return e > 0.f ? e : 0.2f * e; }

DEV unsigned short f2bu(float f) {
    __hip_bfloat16 b = __float2bfloat16(f);
    return *reinterpret_cast<unsigned short*>(&b);
}
DEV float bu2f(unsigned short u) { return __uint_as_float((unsigned)u << 16); }

DEV float loadF(const void* p, size_t i, int f32) {
    if (f32) return ((const float*)p)[i];
    return b2f(((const __hip_bfloat16*)p)[i]);
}

DEV uint4 pack8(const unsigned short* t) {
    uint4 v;
    v.x = (unsigned)t[0] | ((unsigned)t[1] << 16);
    v.y = (unsigned)t[2] | ((unsigned)t[3] << 16);
    v.z = (unsigned)t[4] | ((unsigned)t[5] << 16);
    v.w = (unsigned)t[6] | ((unsigned)t[7] << 16);
    return v;
}

DEV u32x4 pack8v(const unsigned short* t) {
    u32x4 v;
    v.x = (unsigned)t[0] | ((unsigned)t[1] << 16);
    v.y = (unsigned)t[2] | ((unsigned)t[3] << 16);
    v.z = (unsigned)t[4] | ((unsigned)t[5] << 16);
    v.w = (unsigned)t[6] | ((unsigned)t[7] << 16);
    return v;
}

DEV void edge_sd(int i, int E, const int* __restrict__ src, const int* __restrict__ dst,
                 int& s, int& d) {
    if (i < E) { s = src[i]; d = dst[i]; }
    else       { s = d = i - E; }  // self-loops appended as arange(N)
}

// detect helper: wave-level 256-sample scan of one array's low 16-bit halves
DEV int detect_wave(const void* p, int n, int lane) {
    const unsigned short* u16 = (const unsigned short*)p;
    bool insane = false;
#pragma unroll
    for (int r = 0; r < 4; ++r) {
        int idx = lane + r * 64;
        if (idx < n) {
            unsigned short u = u16[idx];
            unsigned e = (u >> 7) & 0xFFu;
            insane |= (e >= 0xC8u) || (e == 0u && (u & 0x7Fu) != 0u);
        }
    }
    return (__ballot(insane) != 0ull) ? 1 : 0;
}

#define G_BIN 128

// ---------------- K1: fused gemm1 (blocks [0,gb)) + binA hist ([gb,gb+G_BIN))
//                  + dtype detect (block gb+G_BIN) ----------------
// gemm1 computes its 4 dtype flags inline (independent of the detect block).
__global__ __launch_bounds__(256) void k_fused1(
    // gemm1
    const void* __restrict__ x, const void* __restrict__ W,
    const void* __restrict__ a_s, const void* __restrict__ a_d,
    __hip_bfloat16* __restrict__ h, float* __restrict__ als, float* __restrict__ ald,
    int N, int gb, int nx, int nW1,
    // binA
    const int* __restrict__ src, const int* __restrict__ dst,
    int* __restrict__ hist, int E, int EA, int chunk,
    // detect (for downstream kernels)
    const void* a5, int n5, const void* a6, int n6, const void* a7, int n7,
    const void* a8, int n8, const void* a9, int n9,
    int* __restrict__ flags)
{
    const int tid = threadIdx.x;
    const int bid = blockIdx.x;

    if (bid >= gb) {
        if (bid == gb + G_BIN) {
            // global detect for downstream consumers (flags[0..8])
            const void* ps[9] = {x, W, a_s, a_d, a5, a6, a7, a8, a9};
            const int   ns[9] = {nx, nW1, 64, 64, n5, n6, n7, n8, n9};
            const int w = tid >> 6, lane = tid & 63;
            for (int k = w; k < 9; k += 4) {
                int f = detect_wave(ps[k], ns[k], lane);
                if (lane == 0) flags[k] = f;
            }
            return;
        }
        // ---- binA: coarse histogram ----
        __shared__ int cnt[256];
        cnt[tid] = 0;
        __syncthreads();
        const int cb = bid - gb;
        const int lo = cb * chunk;
        const int hi = min(lo + chunk, EA);
        for (int i = lo + tid; i < hi; i += 256) {
            int s, d; edge_sd(i, E, src, dst, s, d);
            atomicAdd(&cnt[d >> 8], 1);
        }
        __syncthreads();
        hist[cb * 256 + tid] = cnt[tid];
        return;
    }

    // ---- gemm1: h = x(N,128)@W1(128,64) + fused logits ----
    __shared__ __align__(16) unsigned short sMem[2 * 64 * 136];
    __shared__ float sAs[64], sAd[64];
    __shared__ int sFl[4];
    unsigned short* sA = sMem;
    unsigned short* sB = sMem + 64 * 136;
    float* sOut = (float*)sMem;

    {   // inline dtype detect: wave w checks array w
        const void* ps4[4] = {x, W, a_s, a_d};
        const int   ns4[4] = {nx, nW1, 64, 64};
        const int w = tid >> 6, lane = tid & 63;
        int f = detect_wave(ps4[w], ns4[w], lane);
        if (lane == 0) sFl[w] = f;
    }
    __syncthreads();
    const int fx = sFl[0], fw = sFl[1];

    const int row0 = bid * 64;
    if (tid < 64) sAs[tid] = loadF(a_s, tid, sFl[2]);
    else if (tid < 128) sAd[tid - 64] = loadF(a_d, tid - 64, sFl[3]);

    if (!fx) {
        const uint4* xg = (const uint4*)x;
#pragma unroll
        for (int it = 0; it < 2; ++it) {
            int g = tid + it * 256;
            int r = g >> 4, c16 = g & 15;
            uint4 v = (row0 + r < N) ? xg[(size_t)(row0 + r) * 16 + c16]
                                     : make_uint4(0, 0, 0, 0);
            *(uint4*)(sA + r * 136 + c16 * 8) = v;
        }
    } else {
        for (int i = tid; i < 64 * 128; i += 256) {
            int r = i >> 7, k = i & 127;
            float v = (row0 + r < N) ? ((const float*)x)[(size_t)(row0 + r) * 128 + k] : 0.f;
            sA[r * 136 + k] = f2bu(v);
        }
    }
    if (!fw) {
        const unsigned short* Wg = (const unsigned short*)W;
        const int n = tid & 63;
        int k0 = (tid >> 6) * 8;
#pragma unroll
        for (int rep = 0; rep < 4; ++rep, k0 += 32) {
            unsigned short t[8];
#pragma unroll
            for (int j = 0; j < 8; ++j) t[j] = Wg[(size_t)(k0 + j) * 64 + n];
            *(uint4*)(sB + n * 136 + k0) = pack8(t);
        }
    } else {
        const float* Wg = (const float*)W;
        for (int i = tid; i < 128 * 64; i += 256) {
            int k = i >> 6, n = i & 63;
            sB[n * 136 + k] = f2bu(Wg[i]);
        }
    }
    __syncthreads();

    const int w = tid >> 6, lane = tid & 63;
    const int m0 = w * 16;
    const int qr = lane >> 4;
    const int lc = lane & 15;

    bf16x8 afrag[4];
#pragma unroll
    for (int c = 0; c < 4; ++c) {
        U4 u; u.u = *(const uint4*)(sA + (m0 + lc) * 136 + c * 32 + qr * 8);
        afrag[c] = u.s;
    }
    f32x4 accs[4];
#pragma unroll
    for (int nt = 0; nt < 4; ++nt) {
        f32x4 acc = {0.f, 0.f, 0.f, 0.f};
#pragma unroll
        for (int c = 0; c < 4; ++c) {
            U4 u; u.u = *(const uint4*)(sB + (nt * 16 + lc) * 136 + c * 32 + qr * 8);
            acc = __builtin_amdgcn_mfma_f32_16x16x32_bf16(afrag[c], u.s, acc, 0, 0, 0);
        }
        accs[nt] = acc;
    }
    __syncthreads();

#pragma unroll
    for (int nt = 0; nt < 4; ++nt)
#pragma unroll
        for (int reg = 0; reg < 4; ++reg)
            sOut[(m0 + qr * 4 + reg) * 68 + nt * 16 + lc] = accs[nt][reg];
    __syncthreads();

    {
        const int r = tid >> 2, seg = tid & 3;
        const int row = row0 + r;
        const float* po = sOut + r * 68 + seg * 16;
        float ps = 0.f, pd = 0.f;
        unsigned short ob[16];
#pragma unroll
        for (int i = 0; i < 16; ++i) {
            float v = po[i];
            ps = fmaf(v, sAs[seg * 16 + i], ps);
            pd = fmaf(v, sAd[seg * 16 + i], pd);
            ob[i] = f2bu(v);
        }
        if (row < N) {
            uint4* hp = (uint4*)((unsigned short*)h + (size_t)row * 64 + seg * 16);
            hp[0] = pack8(ob);
            hp[1] = pack8(ob + 8);
        }
        ps += __shfl_xor(ps, 1, 64); ps += __shfl_xor(ps, 2, 64);
        pd += __shfl_xor(pd, 1, 64); pd += __shfl_xor(pd, 2, 64);
        if (seg == 0 && row < N) { als[row] = ps; ald[row] = pd; }
    }
}

// ---------------- binB1: per-bucket scan over block partials; emits btot ----------------
__global__ __launch_bounds__(G_BIN) void k_binB1(
    const int* __restrict__ hist, int* __restrict__ offs_rel,
    int* __restrict__ btot)
{
    __shared__ int sm[G_BIN];
    const int t = threadIdx.x;
    const int b = blockIdx.x;
    int v = hist[t * 256 + b];
    sm[t] = v;
    __syncthreads();
#pragma unroll
    for (int off = 1; off < G_BIN; off <<= 1) {
        int u = (t >= off) ? sm[t - off] : 0;
        __syncthreads();
        sm[t] += u;
        __syncthreads();
    }
    offs_rel[t * 256 + b] = sm[t] - v;
    if (t == G_BIN - 1) btot[b] = sm[t];
}

// ---------------- binC: scatter packed edges; bstart computed via inline LDS scan ----------------
__global__ __launch_bounds__(256) void k_binC(
    const int* __restrict__ src, const int* __restrict__ dst,
    const int* __restrict__ offs_rel, const int* __restrict__ btot,
    unsigned* __restrict__ ebuf, int E, int EA, int chunk)
{
    __shared__ int sm[256];
    __shared__ int cur[256];
    const int tid = threadIdx.x;
    int v = btot[tid];
    sm[tid] = v;
    __syncthreads();
#pragma unroll
    for (int off = 1; off < 256; off <<= 1) {
        int t = (tid >= off) ? sm[tid - off] : 0;
        __syncthreads();
        sm[tid] += t;
        __syncthreads();
    }
    cur[tid] = (sm[tid] - v) + offs_rel[blockIdx.x * 256 + tid];
    __syncthreads();
    const int lo = blockIdx.x * chunk;
    const int hi = min(lo + chunk, EA);
    for (int i = lo + tid; i < hi; i += 256) {
        int s, d; edge_sd(i, E, src, dst, s, d);
        int pos = atomicAdd(&cur[d >> 8], 1);
        ebuf[pos] = ((unsigned)(d & 255) << 17) | (unsigned)s;
    }
}

// ---------------- binD: per-bucket node sort -> row_ptr + col; inline bstart scan ----------------
__global__ __launch_bounds__(256) void k_binD(
    const unsigned* __restrict__ ebuf, const int* __restrict__ btot,
    int* __restrict__ row_ptr, int* __restrict__ col, int N)
{
    __shared__ int sm[256];
    __shared__ int cnt[256];
    __shared__ int pfx[256];
    const int tid = threadIdx.x;
    const int b = blockIdx.x;
    {
        int v = btot[tid];
        sm[tid] = v;
        __syncthreads();
#pragma unroll
        for (int off = 1; off < 256; off <<= 1) {
            int t = (tid >= off) ? sm[tid - off] : 0;
            __syncthreads();
            sm[tid] += t;
            __syncthreads();
        }
    }
    const int lo = (b == 0) ? 0 : sm[b - 1];
    const int hi = sm[b];
    cnt[tid] = 0;
    __syncthreads();
    for (int i = lo + tid; i < hi; i += 256)
        atomicAdd(&cnt[ebuf[i] >> 17], 1);
    __syncthreads();
    const int c = cnt[tid];
    pfx[tid] = c;
    __syncthreads();
#pragma unroll
    for (int off = 1; off < 256; off <<= 1) {
        int t = (tid >= off) ? pfx[tid - off] : 0;
        __syncthreads();
        pfx[tid] += t;
        __syncthreads();
    }
    const int excl = pfx[tid] - c;
    const int d = b * 256 + tid;
    if (d <= N) row_ptr[d] = lo + excl;
    __syncthreads();
    cnt[tid] = lo + excl;              // reuse as absolute cursor
    __syncthreads();
    for (int i = lo + tid; i < hi; i += 256) {
        unsigned v = ebuf[i];
        int pos = atomicAdd(&cnt[v >> 17], 1);
        col[pos] = (int)(v & 0x1FFFFu);
    }
}

// ---------------- MFMA layer-2 GEMM: h2 = relu(agg+b1)@W2(64,64), in-place ----------------
__global__ __launch_bounds__(256) void k_gemm2(
    __hip_bfloat16* __restrict__ agg, const void* __restrict__ b1,
    const void* __restrict__ W, const void* __restrict__ a_s,
    const void* __restrict__ a_d, const int* __restrict__ flags,
    float* __restrict__ als, float* __restrict__ ald, int N)
{
    __shared__ __align__(16) unsigned short sMem[2 * 64 * 72];
    __shared__ float sAs[64], sAd[64], sBias[64];
    unsigned short* sA = sMem;
    unsigned short* sB = sMem + 64 * 72;
    float* sOut = (float*)sMem;

    const int tid = threadIdx.x;
    const int row0 = blockIdx.x * 64;
    const int fw = flags[5];

    if (tid < 64) sAs[tid] = loadF(a_s, tid, flags[6]);
    else if (tid < 128) sAd[tid - 64] = loadF(a_d, tid - 64, flags[7]);
    else if (tid < 192) sBias[tid - 128] = loadF(b1, tid - 128, flags[4]);
    __syncthreads();

    {
        const uint4* ag = (const uint4*)agg;
#pragma unroll
        for (int it = 0; it < 2; ++it) {
            int g = tid + it * 256;
            int r = g >> 3, c8 = g & 7;
            uint4 v = (row0 + r < N) ? ag[(size_t)(row0 + r) * 8 + c8]
                                     : make_uint4(0, 0, 0, 0);
            unsigned short in[8] = {
                (unsigned short)(v.x & 0xFFFF), (unsigned short)(v.x >> 16),
                (unsigned short)(v.y & 0xFFFF), (unsigned short)(v.y >> 16),
                (unsigned short)(v.z & 0xFFFF), (unsigned short)(v.z >> 16),
                (unsigned short)(v.w & 0xFFFF), (unsigned short)(v.w >> 16)};
            unsigned short ob[8];
#pragma unroll
            for (int j = 0; j < 8; ++j) {
                float t = bu2f(in[j]) + sBias[c8 * 8 + j];
                ob[j] = f2bu(t > 0.f ? t : 0.f);
            }
            *(uint4*)(sA + r * 72 + c8 * 8) = pack8(ob);
        }
    }
    if (!fw) {
        const unsigned short* Wg = (const unsigned short*)W;
        const int n = tid & 63;
        int k0 = (tid >> 6) * 8;
#pragma unroll
        for (int rep = 0; rep < 2; ++rep, k0 += 32) {
            unsigned short t[8];
#pragma unroll
            for (int j = 0; j < 8; ++j) t[j] = Wg[(size_t)(k0 + j) * 64 + n];
            *(uint4*)(sB + n * 72 + k0) = pack8(t);
        }
    } else {
        const float* Wg = (const float*)W;
        for (int i = tid; i < 64 * 64; i += 256) {
            int k = i >> 6, n = i & 63;
            sB[n * 72 + k] = f2bu(Wg[i]);
        }
    }
    __syncthreads();

    const int w = tid >> 6, lane = tid & 63;
    const int m0 = w * 16;
    const int qr = lane >> 4, lc = lane & 15;

    bf16x8 afrag[2];
#pragma unroll
    for (int c = 0; c < 2; ++c) {
        U4 u; u.u = *(const uint4*)(sA + (m0 + lc) * 72 + c * 32 + qr * 8);
        afrag[c] = u.s;
    }
    f32x4 accs[4];
#pragma unroll
    for (int nt = 0; nt < 4; ++nt) {
        f32x4 acc = {0.f, 0.f, 0.f, 0.f};
#pragma unroll
        for (int c = 0; c < 2; ++c) {
            U4 u; u.u = *(const uint4*)(sB + (nt * 16 + lc) * 72 + c * 32 + qr * 8);
            acc = __builtin_amdgcn_mfma_f32_16x16x32_bf16(afrag[c], u.s, acc, 0, 0, 0);
        }
        accs[nt] = acc;
    }
    __syncthreads();
#pragma unroll
    for (int nt = 0; nt < 4; ++nt)
#pragma unroll
        for (int reg = 0; reg < 4; ++reg)
            sOut[(m0 + qr * 4 + reg) * 68 + nt * 16 + lc] = accs[nt][reg];
    __syncthreads();

    {
        const int r = tid >> 2, seg = tid & 3;
        const int row = row0 + r;
        const float* po = sOut + r * 68 + seg * 16;
        float ps = 0.f, pd = 0.f;
        unsigned short ob[16];
#pragma unroll
        for (int i = 0; i < 16; ++i) {
            float v = po[i];
            ps = fmaf(v, sAs[seg * 16 + i], ps);
            pd = fmaf(v, sAd[seg * 16 + i], pd);
            ob[i] = f2bu(v);
        }
        if (row < N) {
            uint4* hp = (uint4*)((unsigned short*)agg + (size_t)row * 64 + seg * 16);
            hp[0] = pack8(ob);
            hp[1] = pack8(ob + 8);
        }
        ps += __shfl_xor(ps, 1, 64); ps += __shfl_xor(ps, 2, 64);
        pd += __shfl_xor(pd, 1, 64); pd += __shfl_xor(pd, 2, 64);
        if (seg == 0 && row < N) { als[row] = ps; ald[row] = pd; }
    }
}

// ---------------- CSR gather (r12 structure: persistent, per-cluster exit) ----------------
__global__ __launch_bounds__(256) void k_gather(
    const int* __restrict__ row_ptr, const int* __restrict__ col,
    const float* __restrict__ als, const float* __restrict__ ald,
    const __hip_bfloat16* __restrict__ h,
    __hip_bfloat16* __restrict__ agg_out,
    void* __restrict__ final_out,
    const void* __restrict__ bias, const int* __restrict__ flags, int N)
{
    const int tid = threadIdx.x;
    const int lane = tid & 63;
    const int eg = lane >> 3, fg = lane & 7;
    const int wid = blockIdx.x * 4 + (tid >> 6);
    const int nw  = gridDim.x * 4;

    for (int d = wid; d < N; d += nw) {
        const float aldd = ald[d];
        const int beg = row_ptr[d], end = row_ptr[d + 1];
        float acc[8] = {0.f,0.f,0.f,0.f,0.f,0.f,0.f,0.f};
        float den = 0.f;
        for (int j = beg + eg; j < end; j += 8) {   // per-cluster exit
            const int s = col[j];
            const float w = __expf(lrelu(als[s] + aldd));
            den += w;
            const uint4 hv = *reinterpret_cast<const uint4*>(h + (size_t)s * 64 + fg * 8);
            acc[0] = fmaf(w, __uint_as_float(hv.x << 16),          acc[0]);
            acc[1] = fmaf(w, __uint_as_float(hv.x & 0xFFFF0000u),  acc[1]);
            acc[2] = fmaf(w, __uint_as_float(hv.y << 16),          acc[2]);
            acc[3] = fmaf(w, __uint_as_float(hv.y & 0xFFFF0000u),  acc[3]);
            acc[4] = fmaf(w, __uint_as_float(hv.z << 16),          acc[4]);
            acc[5] = fmaf(w, __uint_as_float(hv.z & 0xFFFF0000u),  acc[5]);
            acc[6] = fmaf(w, __uint_as_float(hv.w << 16),          acc[6]);
            acc[7] = fmaf(w, __uint_as_float(hv.w & 0xFFFF0000u),  acc[7]);
        }
#pragma unroll
        for (int off = 8; off <= 32; off <<= 1) {
            den += __shfl_xor(den, off, 64);
#pragma unroll
            for (int k = 0; k < 8; ++k) acc[k] += __shfl_xor(acc[k], off, 64);
        }
        if (eg == 0) {
            const float inv = 1.f / den;
            if (final_out) {
                float vb[8];
#pragma unroll
                for (int k = 0; k < 8; ++k) vb[k] = acc[k] * inv + loadF(bias, fg * 8 + k, flags[8]);
                if (flags[0]) {
                    float* o = (float*)final_out + (size_t)d * 64 + fg * 8;
                    f32x4 o0 = {vb[0], vb[1], vb[2], vb[3]};
                    f32x4 o1 = {vb[4], vb[5], vb[6], vb[7]};
                    __builtin_nontemporal_store(o0, (f32x4*)o);
                    __builtin_nontemporal_store(o1, (f32x4*)(o + 4));
                } else {
                    unsigned short ob[8];
#pragma unroll
                    for (int k = 0; k < 8; ++k) ob[k] = f2bu(vb[k]);
                    __builtin_nontemporal_store(pack8v(ob),
                        reinterpret_cast<u32x4*>((__hip_bfloat16*)final_out + (size_t)d * 64 + fg * 8));
                }
            } else {
                unsigned short ob[8];
#pragma unroll
                for (int k = 0; k < 8; ++k) ob[k] = f2bu(acc[k] * inv);
                __builtin_nontemporal_store(pack8v(ob),
                    reinterpret_cast<u32x4*>(agg_out + (size_t)d * 64 + fg * 8));
            }
        }
    }
}

extern "C" void kernel_launch(void* const* d_in, const int* in_sizes, int n_in,
                              void* d_out, int out_size, void* d_ws, size_t ws_size,
                              hipStream_t stream)
{
    const void* x   = d_in[0];
    const int*  ei  = (const int*)d_in[1];
    const void* W1  = d_in[2];
    const void* as1 = d_in[3];
    const void* ad1 = d_in[4];
    const void* b1  = d_in[5];
    const void* W2  = d_in[6];
    const void* as2 = d_in[7];
    const void* ad2 = d_in[8];
    const void* b2  = d_in[9];

    const int N  = in_sizes[0] / 128;   // 50000
    const int E  = in_sizes[1] / 2;     // 800000
    const int EA = E + N;
    const int* src = ei;
    const int* dst = ei + E;

    uintptr_t base = (uintptr_t)d_ws;
    auto alloc = [&](size_t bytes) { uintptr_t p = base; base += (bytes + 63) & ~(size_t)63; return p; };
    int*      flags    = (int*)alloc(64 * 4);
    float*    als      = (float*)alloc((size_t)N * 4);
    float*    ald      = (float*)alloc((size_t)N * 4);
    int*      row_ptr  = (int*)alloc((size_t)(N + 1) * 4);
    int*      hist     = (int*)alloc((size_t)G_BIN * 256 * 4);
    int*      offs_rel = (int*)alloc((size_t)G_BIN * 256 * 4);
    int*      btot     = (int*)alloc(256 * 4);
    unsigned* ebuf     = (unsigned*)alloc((size_t)EA * 4);
    int*      col      = (int*)alloc((size_t)EA * 4);
    __hip_bfloat16* hbuf   = (__hip_bfloat16*)alloc((size_t)N * 64 * 2);
    __hip_bfloat16* aggbuf = (__hip_bfloat16*)alloc((size_t)N * 64 * 2);

    const int gatherb = 2048;             // persistent: 8 blocks/CU resident
    const int gb  = (N + 63) / 64;        // gemm blocks: 64 rows/block
    const int NBK = (N + 255) / 256;      // dst buckets (<= 256)
    const int chunk = (EA + G_BIN - 1) / G_BIN;

    // ---- K1: gemm1 || binA || detect (all independent) ----
    k_fused1<<<gb + G_BIN + 1, 256, 0, stream>>>(
        x, W1, as1, ad1, hbuf, als, ald, N, gb, in_sizes[0], in_sizes[2],
        src, dst, hist, E, EA, chunk,
        b1, in_sizes[5], W2, in_sizes[6], as2, in_sizes[7], ad2, in_sizes[8],
        b2, in_sizes[9], flags);
    // ---- CSR finish ----
    k_binB1<<<256, G_BIN, 0, stream>>>(hist, offs_rel, btot);
    k_binC<<<G_BIN, 256, 0, stream>>>(src, dst, offs_rel, btot, ebuf, E, EA, chunk);
    k_binD<<<NBK, 256, 0, stream>>>(ebuf, btot, row_ptr, col, N);

    // ---- layer 1 gather ----
    k_gather<<<gatherb, 256, 0, stream>>>(row_ptr, col, als, ald, hbuf, aggbuf,
                                          nullptr, nullptr, flags, N);
    // ---- layer 2 ----
    k_gemm2<<<gb, 256, 0, stream>>>(aggbuf, b1, W2, as2, ad2, flags, als, ald, N);
    k_gather<<<gatherb, 256, 0, stream>>>(row_ptr, col, als, ald, aggbuf, nullptr,
                                          d_out, b2, flags, N);
    (void)out_size; (void)ws_size; (void)n_in;
}